// Round 2
// baseline (4877.388 us; speedup 1.0000x reference)
//
#include <hip/hip_runtime.h>

// BiLSTM B=512 T=1024 D=64 H=50, 2 layers bidir, FC on h[:,-1].
// MFMA split-bf16 scan: 16 sequences per block (M=16), weights in register
// B-frags, fused x-GEMM per W-step window with one-window-ahead prefetch.
//   scan l0: 64 blocks (32 row-groups x 2 dirs), K=64,  writes h_l0 (B,T,100) fp32
//   scan l1f: 32 blocks,                        K=100, writes h1cat cols 0..49
//   l1b: single step at t=T-1 (h0=c0=0 -> no Whh term), cols 50..99
//   fc:  dot(h1cat, fc_w)+fc_b

#define BATCH 512
#define TT    1024
#define HH    50
#define GG    200
#define NT    13      // N-tiles of 16 (200 -> 208)
#define GP    212     // gbuf padded row stride (floats)
#define HPAD  72      // h-frag LDS row stride (bf16) -> kills bank conflicts

typedef __attribute__((ext_vector_type(4))) float  f32x4;
typedef __attribute__((ext_vector_type(8))) short  bf16x8;

__device__ __forceinline__ float sigf(float x)     { return 1.f / (1.f + __expf(-x)); }
__device__ __forceinline__ float tanhfast(float x) { return 1.f - 2.f / (__expf(2.f * x) + 1.f); }

// split fp32 -> bf16 hi + bf16 lo (truncation; lo captures next 8 mantissa bits)
__device__ __forceinline__ void split8(const float (&v)[8], bf16x8& hi, bf16x8& lo) {
#pragma unroll
  for (int j = 0; j < 8; ++j) {
    unsigned b = __float_as_uint(v[j]);
    hi[j] = (short)(b >> 16);
    float rem = v[j] - __uint_as_float(b & 0xFFFF0000u);
    lo[j] = (short)(__float_as_uint(rem) >> 16);
  }
}

// one-time scalar weight load into a B-fragment (B[k][col], k = ks*32+8*(l>>4)+j, col = n*16+(l&15))
__device__ __forceinline__ void load_wfrag(const float* __restrict__ W, int ld, int kvalid,
                                           int n, int ks, int lane, bf16x8& hi, bf16x8& lo) {
  const int col = n * 16 + (lane & 15);
  const int kb  = ks * 32 + ((lane >> 4) << 3);
  float v[8];
#pragma unroll
  for (int j = 0; j < 8; ++j) {
    const int k = kb + j;
    v[j] = (col < GG && k < kvalid) ? W[col * ld + k] : 0.f;
  }
  split8(v, hi, lo);
}

template<int DINK, int KS, int W, bool L0>
__global__ __launch_bounds__(256, 1) void lstm_scan_mfma(
    const float* __restrict__ xin,
    const float* __restrict__ Wih_f, const float* __restrict__ Whh_f,
    const float* __restrict__ bih_f, const float* __restrict__ bhh_f,
    const float* __restrict__ Wih_b, const float* __restrict__ Whh_b,
    const float* __restrict__ bih_b, const float* __restrict__ bhh_b,
    float* __restrict__ hseq,      // L0: (B,T,100) fp32
    float* __restrict__ hlast)     // !L0: (B,100) cols 0..49
{
  const int tid  = threadIdx.x;
  const int lane = tid & 63;
  const int wid  = tid >> 6;
  int dir, rg;
  if (L0) { dir = blockIdx.x & 1; rg = blockIdx.x >> 1; }
  else    { dir = 0;              rg = blockIdx.x; }
  const int r0 = rg * 16;

  const float* Wih = dir ? Wih_b : Wih_f;
  const float* Whh = dir ? Whh_b : Whh_f;
  const float* bih = dir ? bih_b : bih_f;
  const float* bhh = dir ? bhh_b : bhh_f;

  __shared__ short h_hi[16][HPAD];
  __shared__ short h_lo[16][HPAD];
  __shared__ float gbuf[16][GP];

  for (int idx = tid; idx < 16 * HPAD; idx += 256) {
    (&h_hi[0][0])[idx] = 0; (&h_lo[0][0])[idx] = 0;
  }

  // ---------------- weights -> register fragments (read once) ----------------
  bf16x8 wih_hi[4][KS], wih_lo[4][KS];
  bf16x8 whh_hi[4][2],  whh_lo[4][2];
#pragma unroll
  for (int i = 0; i < 4; ++i) {
    const int n = wid * 4 + i;
    if (n < NT) {
#pragma unroll
      for (int ks = 0; ks < KS; ++ks)
        load_wfrag(Wih, DINK, DINK, n, ks, lane, wih_hi[i][ks], wih_lo[i][ks]);
#pragma unroll
      for (int ks = 0; ks < 2; ++ks)
        load_wfrag(Whh, HH, HH, n, ks, lane, whh_hi[i][ks], whh_lo[i][ks]);
    }
  }

  // ---------------- elementwise ownership: thread t<200 owns (r=rq+q, j) ------
  const bool ew = tid < 4 * HH;
  const int  j  = tid % HH;
  const int  rq = (tid / HH) * 4;
  float c[4] = {0.f, 0.f, 0.f, 0.f};
  float bI = 0.f, bF = 0.f, bG = 0.f, bO = 0.f;
  if (ew) {
    bI = bih[j]          + bhh[j];
    bF = bih[HH + j]     + bhh[HH + j];
    bG = bih[2*HH + j]   + bhh[2*HH + j];
    bO = bih[3*HH + j]   + bhh[3*HH + j];
  }

  // ---------------- x window machinery ----------------
  float  xr[W][KS][8];   // raw fp32 x for NEXT window (prefetched)
  f32x4  xp[W][4];       // xp accumulators for CURRENT window

  auto load_win = [&](int tb) {
#pragma unroll
    for (int tw = 0; tw < W; ++tw) {
      const int tl = tb + tw;
      const int tg = dir ? (TT - 1 - tl) : tl;
      const float* base = xin + ((size_t)(r0 + (lane & 15)) * TT + tg) * DINK;
#pragma unroll
      for (int ks = 0; ks < KS; ++ks) {
        const int kb = ks * 32 + ((lane >> 4) << 3);
        if (kb + 8 <= DINK) {
          const f32x4 a = *(const f32x4*)(base + kb);
          const f32x4 b = *(const f32x4*)(base + kb + 4);
#pragma unroll
          for (int q = 0; q < 4; ++q) { xr[tw][ks][q] = a[q]; xr[tw][ks][4+q] = b[q]; }
        } else if (kb < DINK) {        // l1 tail: k = 96..99
          const f32x4 a = *(const f32x4*)(base + kb);
#pragma unroll
          for (int q = 0; q < 4; ++q) { xr[tw][ks][q] = a[q]; xr[tw][ks][4+q] = 0.f; }
        } else {
#pragma unroll
          for (int q = 0; q < 8; ++q) xr[tw][ks][q] = 0.f;
        }
      }
    }
  };

  auto compute_xp = [&]() {
#pragma unroll
    for (int tw = 0; tw < W; ++tw) {
      bf16x8 ah[KS], al[KS];
#pragma unroll
      for (int ks = 0; ks < KS; ++ks) split8(xr[tw][ks], ah[ks], al[ks]);
#pragma unroll
      for (int i = 0; i < 4; ++i) {
        if (wid * 4 + i < NT) {
          f32x4 acc = {0.f, 0.f, 0.f, 0.f};
#pragma unroll
          for (int ks = 0; ks < KS; ++ks) {
            acc = __builtin_amdgcn_mfma_f32_16x16x32_bf16(ah[ks], wih_hi[i][ks], acc, 0, 0, 0);
            acc = __builtin_amdgcn_mfma_f32_16x16x32_bf16(al[ks], wih_hi[i][ks], acc, 0, 0, 0);
            acc = __builtin_amdgcn_mfma_f32_16x16x32_bf16(ah[ks], wih_lo[i][ks], acc, 0, 0, 0);
          }
          xp[tw][i] = acc;
        }
      }
    }
  };

  load_win(0);
  compute_xp();          // window 0 -> xp
  load_win(W);           // window 1 -> xr (in flight across first steps)
  __syncthreads();

  // ---------------- sequential scan ----------------
  for (int tb = 0; tb < TT; tb += W) {
#pragma unroll
    for (int tw = 0; tw < W; ++tw) {
      const int t = tb + tw;

      // recurrent part: D = xp + H @ WhhT  (split-bf16, 3 products)
      f32x4 D[4];
#pragma unroll
      for (int i = 0; i < 4; ++i) D[i] = xp[tw][i];
#pragma unroll
      for (int ks = 0; ks < 2; ++ks) {
        const bf16x8 ah = *(const bf16x8*)&h_hi[lane & 15][ks * 32 + ((lane >> 4) << 3)];
        const bf16x8 al = *(const bf16x8*)&h_lo[lane & 15][ks * 32 + ((lane >> 4) << 3)];
#pragma unroll
        for (int i = 0; i < 4; ++i) {
          if (wid * 4 + i < NT) {
            D[i] = __builtin_amdgcn_mfma_f32_16x16x32_bf16(ah, whh_hi[i][ks], D[i], 0, 0, 0);
            D[i] = __builtin_amdgcn_mfma_f32_16x16x32_bf16(al, whh_hi[i][ks], D[i], 0, 0, 0);
            D[i] = __builtin_amdgcn_mfma_f32_16x16x32_bf16(ah, whh_lo[i][ks], D[i], 0, 0, 0);
          }
        }
      }
#pragma unroll
      for (int i = 0; i < 4; ++i) {
        const int n = wid * 4 + i;
        if (n < NT) {
          const int col = n * 16 + (lane & 15);
          const int rb  = (lane >> 4) * 4;
#pragma unroll
          for (int q = 0; q < 4; ++q) gbuf[rb + q][col] = D[i][q];   // D: col=lane&15, row=(lane>>4)*4+q
        }
      }
      __syncthreads();

      // elementwise: gates -> c,h; write h to LDS frags (+ global)
      if (ew) {
        const int tg = dir ? (TT - 1 - t) : t;
#pragma unroll
        for (int q = 0; q < 4; ++q) {
          const int r = rq + q;
          const float gi = gbuf[r][j]          + bI;
          const float gf = gbuf[r][HH + j]     + bF;
          const float gg = gbuf[r][2*HH + j]   + bG;
          const float go = gbuf[r][3*HH + j]   + bO;
          const float iv = sigf(gi), fv = sigf(gf), gv = tanhfast(gg), ov = sigf(go);
          c[q] = fv * c[q] + iv * gv;
          const float h = ov * tanhfast(c[q]);
          const unsigned hb = __float_as_uint(h);
          h_hi[r][j] = (short)(hb >> 16);
          const float rem = h - __uint_as_float(hb & 0xFFFF0000u);
          h_lo[r][j] = (short)(__float_as_uint(rem) >> 16);
          if (L0) hseq[((size_t)(r0 + r) * TT + tg) * 100 + dir * HH + j] = h;
          else if (t == TT - 1) hlast[(r0 + r) * 100 + j] = h;
        }
      }

      // window boundary: materialize next window's xp, then prefetch the one after
      if (tw == W - 1) {
        if (tb + W < TT) {
          compute_xp();
          if (tb + 2 * W < TT) load_win(tb + 2 * W);
        }
      }
      __syncthreads();
    }
  }
}

// ------------- Layer 1 backward at t=T-1: single step, h0=c0=0 -> no Whh term. ----
__global__ __launch_bounds__(256) void l1b_step(
    const float* __restrict__ hl0,
    const float* __restrict__ Wih,
    const float* __restrict__ bih, const float* __restrict__ bhh,
    float* __restrict__ h1cat)
{
    const int row = blockIdx.x;
    const int tid = threadIdx.x;
    __shared__ float in_s[100];
    __shared__ float gbuf[4 * HH];

    const float* inp = hl0 + ((size_t)row * TT + (TT - 1)) * 100;
    if (tid < 100) in_s[tid] = inp[tid];
    __syncthreads();

    if (tid < 4 * HH) {
        float acc = bih[tid] + bhh[tid];
#pragma unroll
        for (int k = 0; k < 100; ++k) acc += in_s[k] * Wih[tid * 100 + k];
        gbuf[tid] = acc;
    }
    __syncthreads();
    if (tid < HH) {
        float iv = sigf(gbuf[tid]);
        float gv = tanhfast(gbuf[2 * HH + tid]);
        float ov = sigf(gbuf[3 * HH + tid]);
        float cc = iv * gv;
        h1cat[row * 100 + HH + tid] = ov * tanhfast(cc);
    }
}

__global__ void fc_out(const float* __restrict__ h1cat,
                       const float* __restrict__ fcw, const float* __restrict__ fcb,
                       float* __restrict__ out)
{
    const int b = blockIdx.x * blockDim.x + threadIdx.x;
    if (b < BATCH) {
        float acc = fcb[0];
#pragma unroll 4
        for (int k = 0; k < 100; ++k) acc += h1cat[b * 100 + k] * fcw[k];
        out[b] = acc;
    }
}

extern "C" void kernel_launch(void* const* d_in, const int* in_sizes, int n_in,
                              void* d_out, int out_size, void* d_ws, size_t ws_size,
                              hipStream_t stream) {
    const float* x        = (const float*)d_in[0];
    const float* Wih_l0f  = (const float*)d_in[1];
    const float* Whh_l0f  = (const float*)d_in[2];
    const float* bih_l0f  = (const float*)d_in[3];
    const float* bhh_l0f  = (const float*)d_in[4];
    const float* Wih_l0b  = (const float*)d_in[5];
    const float* Whh_l0b  = (const float*)d_in[6];
    const float* bih_l0b  = (const float*)d_in[7];
    const float* bhh_l0b  = (const float*)d_in[8];
    const float* Wih_l1f  = (const float*)d_in[9];
    const float* Whh_l1f  = (const float*)d_in[10];
    const float* bih_l1f  = (const float*)d_in[11];
    const float* bhh_l1f  = (const float*)d_in[12];
    const float* Wih_l1b  = (const float*)d_in[13];
    /* Whh_l1b (d_in[14]) unused: h0=0 for the single backward step at t=T-1 */
    const float* bih_l1b  = (const float*)d_in[15];
    const float* bhh_l1b  = (const float*)d_in[16];
    const float* fc_w     = (const float*)d_in[17];
    const float* fc_b     = (const float*)d_in[18];

    float* hl0   = (float*)d_ws;                       // (B,T,100) fp32 = 209.7 MB
    float* h1cat = hl0 + (size_t)BATCH * TT * 100;     // (B,100)

    lstm_scan_mfma<64, 2, 4, true><<<dim3(2 * BATCH / 16), dim3(256), 0, stream>>>(
        x, Wih_l0f, Whh_l0f, bih_l0f, bhh_l0f,
           Wih_l0b, Whh_l0b, bih_l0b, bhh_l0b, hl0, nullptr);

    lstm_scan_mfma<100, 4, 2, false><<<dim3(BATCH / 16), dim3(256), 0, stream>>>(
        hl0, Wih_l1f, Whh_l1f, bih_l1f, bhh_l1f,
             Wih_l1f, Whh_l1f, bih_l1f, bhh_l1f, nullptr, h1cat);

    l1b_step<<<dim3(BATCH), dim3(256), 0, stream>>>(hl0, Wih_l1b, bih_l1b, bhh_l1b, h1cat);
    fc_out<<<dim3(2), dim3(256), 0, stream>>>(h1cat, fc_w, fc_b, (float*)d_out);
}